// Round 4
// baseline (338.502 us; speedup 1.0000x reference)
//
#include <hip/hip_runtime.h>
#include <hip/hip_bf16.h>

typedef __attribute__((ext_vector_type(8))) short short8;
typedef __attribute__((ext_vector_type(4))) float floatx4;

#define C_INN 256
#define T_N   8
#define H_N   56
#define W_N   56
#define C_OUTN 256
#define HW_N  (H_N * W_N)
#define THW   (T_N * HW_N)
#define NTAP  9
#define LDX_S 40   // bf16 elems per px row (32 + 8 pad)

// async global->LDS, 16B per lane; LDS dest = wave-uniform base + lane*16
#define GLOAD_LDS16(gp, lp) \
  __builtin_amdgcn_global_load_lds((const __attribute__((address_space(1))) void*)(gp), \
                                   (__attribute__((address_space(3))) void*)(lp), 16, 0, 0)

// -------- prep: weight (C_OUT, C_IN, 1, 3, 3) fp32 -> wb pre-swizzled for linear LDS staging
// wb layout: [g4 = cg*4+mtile][chunk = (tap*4+quad)*64 + r][e=0..7]  (16B chunks)
// chunk content = A[o = mtile*64+r][tap][ci = cg*32 + quad*8 + e]
__global__ void prep_weight(const float* __restrict__ w, __hip_bfloat16* __restrict__ wb) {
    int idx = blockIdx.x * blockDim.x + threadIdx.x;
    if (idx >= C_OUTN * NTAP * C_INN) return;
    int e    = idx & 7;
    int c    = (idx >> 3) % 2304;      // chunk within (cg,mtile) slice
    int g4   = (idx >> 3) / 2304;      // cg*4 + mtile
    int r    = c & 63;
    int tq   = c >> 6;                 // tap*4 + quad, 0..35
    int quad = tq & 3, tap = tq >> 2;
    int cg = g4 >> 2, mtile = g4 & 3;
    int o  = mtile * 64 + r;
    int ci = cg * 32 + quad * 8 + e;
    wb[idx] = __float2bfloat16(w[(o * C_INN + ci) * NTAP + tap]);
}

// -------- main: M=64 x N=256 block tile; A via global_load_lds (linear, conflict-free);
// X halo T14-prefetched into regs during previous cg's compute --------
__global__ __launch_bounds__(256, 2) void tada_conv(
    const float* __restrict__ x, const float* __restrict__ alpha,
    const __hip_bfloat16* __restrict__ wb, const float* __restrict__ bias,
    float* __restrict__ out)
{
    // lA: linear 16B chunks, chunk = (tap*4+quad)*64 + r  -> 36864 B
    __shared__ __hip_bfloat16 lA[2304 * 8];
    // lX[px][ci32 (+8 pad)]: 340 px (10h x 34w halo)     -> 27200 B
    __shared__ __hip_bfloat16 lX[340 * LDX_S];

    const int tid   = threadIdx.x;
    const int mtile = blockIdx.x;          // 0..3   (c_out tile of 64)
    const int ntile = blockIdx.y;          // 0..13  (7 h-tiles x 2 w-tiles)
    const int bt    = blockIdx.z;          // 0..31
    const int b = bt >> 3, t = bt & 7;
    const int h0 = (ntile % 7) * 8;
    const int w0 = (ntile / 7) * 32;

    const int wn   = tid >> 6;             // wave 0..3 -> px quarter
    const int lane = tid & 63;
    const int col = lane & 15, quad = lane >> 4;

    // X staging decomposition: 8 ci-quads x 32 px-lanes
    const int cil = tid >> 5;   // 0..7
    const int pxl = tid & 31;   // 0..31

    // ---- cg-invariant X halo offsets (sentinel -1 = outside image) ----
    int xoff[11];
#pragma unroll
    for (int it = 0; it < 11; ++it) {
        int px = pxl + it * 32;
        int hi = px / 34;
        int wi = px - hi * 34;
        int hh = h0 - 1 + hi;
        int ww = w0 - 1 + wi;
        bool inimg = (px < 340) && ((unsigned)hh < (unsigned)H_N) && ((unsigned)ww < (unsigned)W_N);
        xoff[it] = inimg ? (hh * W_N + ww) : -1;
    }

    floatx4 acc[4][4];
#pragma unroll
    for (int i = 0; i < 4; ++i)
#pragma unroll
        for (int j = 0; j < 4; ++j)
            acc[i][j] = (floatx4){0.f, 0.f, 0.f, 0.f};

    const long xbase = ((long)b * C_INN) * THW + (long)t * HW_N;
    const int  abase = b * C_INN * T_N + t;

    // ---- T14 prefetch state: raw fp32 X values + alpha for the NEXT cg ----
    floatx4 pX[11];
    float   pa0, pa1, pa2, pa3;

    auto PREFETCH = [&](int cgp) {
        const int ci0 = cgp * 32 + cil * 4;
        pa0 = alpha[abase + (ci0 + 0) * T_N];
        pa1 = alpha[abase + (ci0 + 1) * T_N];
        pa2 = alpha[abase + (ci0 + 2) * T_N];
        pa3 = alpha[abase + (ci0 + 3) * T_N];
        const float* xc = x + xbase + (long)ci0 * THW;
#pragma unroll
        for (int it = 0; it < 11; ++it) {
            float v0 = 0.f, v1 = 0.f, v2 = 0.f, v3 = 0.f;
            if (xoff[it] >= 0) {
                const float* xp = xc + xoff[it];
                v0 = xp[0];
                v1 = xp[THW];
                v2 = xp[2 * THW];
                v3 = xp[3 * THW];
            }
            pX[it] = (floatx4){v0, v1, v2, v3};
        }
    };

    PREFETCH(0);

    for (int cg = 0; cg < 8; ++cg) {
        __syncthreads();   // previous cg's lA/lX reads done

        // ---- stage A: 9 x global_load_lds (16B/lane), linear LDS, L2-resident src ----
        {
            const __hip_bfloat16* wsrc = wb + ((long)(cg * 4 + mtile) * 2304) * 8;
            const int cb = wn * 64;     // wave-uniform chunk base
#pragma unroll
            for (int it = 0; it < 9; ++it) {
                GLOAD_LDS16(wsrc + (long)(it * 256 + cb + lane) * 8,
                            (char*)lA + (it * 256 + cb) * 16);
            }
        }

        // ---- write X halo: scale by alpha, cvt to bf16, ds_write_b64 ----
#pragma unroll
        for (int it = 0; it < 11; ++it) {
            int px = pxl + it * 32;
            if (it < 10 || pxl < 20) {      // px < 340
                union { __hip_bfloat16 h[4]; unsigned long long u; } pk;
                pk.h[0] = __float2bfloat16(pX[it][0] * pa0);
                pk.h[1] = __float2bfloat16(pX[it][1] * pa1);
                pk.h[2] = __float2bfloat16(pX[it][2] * pa2);
                pk.h[3] = __float2bfloat16(pX[it][3] * pa3);
                *reinterpret_cast<unsigned long long*>(&lX[px * LDX_S + cil * 4]) = pk.u;
            }
        }

        __syncthreads();   // lA (vmcnt) + lX (lgkm) staged

        // ---- issue next cg's X loads now; latency hides under this cg's MFMA ----
        if (cg < 7) PREFETCH(cg + 1);

        // ---- 9 taps, barrier-free: 8 ds_read_b128 + 16 MFMA per tap ----
        const __hip_bfloat16* lAr = lA + quad * 512 + col * 8;   // + tap*2048 + mi*128 (imm)
#pragma unroll
        for (int kh = 0; kh < 3; ++kh) {
#pragma unroll
            for (int kw = 0; kw < 3; ++kw) {
                const int tap = kh * 3 + kw;
                short8 af[4], bf[4];
#pragma unroll
                for (int mi = 0; mi < 4; ++mi)
                    af[mi] = *(const short8*)(lAr + tap * 2048 + mi * 128);
#pragma unroll
                for (int ni = 0; ni < 4; ++ni) {
                    int g  = wn * 4 + ni;                       // 16-px group 0..15
                    int px = ((g >> 1) + kh) * 34 + (g & 1) * 16 + col + kw;
                    bf[ni] = *(const short8*)(lX + px * LDX_S + quad * 8);
                }
#pragma unroll
                for (int mi = 0; mi < 4; ++mi)
#pragma unroll
                    for (int ni = 0; ni < 4; ++ni)
                        acc[mi][ni] = __builtin_amdgcn_mfma_f32_16x16x32_bf16(
                            af[mi], bf[ni], acc[mi][ni], 0, 0, 0);
            }
        }
    }

    // ---- epilogue: bias + store (C/D layout: col=lane&15, row=quad*4+reg) ----
#pragma unroll
    for (int mi = 0; mi < 4; ++mi) {
        const floatx4 bv = *(const floatx4*)(bias + mtile * 64 + mi * 16 + quad * 4);
#pragma unroll
        for (int ni = 0; ni < 4; ++ni) {
            int n  = wn * 64 + ni * 16 + col;
            int ph = n >> 5, pw = n & 31;
            if (w0 + pw < W_N) {
#pragma unroll
                for (int r = 0; r < 4; ++r) {
                    int m = mtile * 64 + mi * 16 + quad * 4 + r;
                    out[(((long)b * C_OUTN + m) * T_N + t) * HW_N + (h0 + ph) * W_N + (w0 + pw)]
                        = acc[mi][ni][r] + bv[r];
                }
            }
        }
    }
}

extern "C" void kernel_launch(void* const* d_in, const int* in_sizes, int n_in,
                              void* d_out, int out_size, void* d_ws, size_t ws_size,
                              hipStream_t stream) {
    const float* x      = (const float*)d_in[0];
    const float* alpha  = (const float*)d_in[1];
    const float* weight = (const float*)d_in[2];
    const float* bias   = (const float*)d_in[3];
    float* out = (float*)d_out;

    __hip_bfloat16* wb = (__hip_bfloat16*)d_ws;   // 256*9*256 bf16 = 1.18 MB (pre-swizzled)

    int nprep = C_OUTN * NTAP * C_INN;
    prep_weight<<<(nprep + 255) / 256, 256, 0, stream>>>(weight, wb);

    dim3 grid(4, 14, 32);
    tada_conv<<<grid, 256, 0, stream>>>(x, alpha, wb, bias, out);
}